// Round 7
// baseline (143.170 us; speedup 1.0000x reference)
//
#include <hip/hip_runtime.h>

// SparseMatmul3D: out[b,n,m] = sum_k x[b,n,k] * y[b,m,k]
// B=4, N=M=4096, D=64, fp32 in/out. Write-bound (268 MB out, floor ~38us @7TB/s).
// R1: 128x128 tiles, direct 64B-segment stores    -> 89.7 us (~3.0 TB/s)
// R2: 128x128 tiles, LDS-staged 512B runs         -> 94.5 us
// R3: 32-row slabs, lockstep m-walk               -> 163 us (1.6 TB/s channel alias)
// R4: slab + stagger + cvt_pk asm                 -> NaN (asm miscompile; banned)
// R5: slab + stagger, clean                       -> 132 us (slabs structurally bad)
// R6: 16x512 tiles, LDS epilogue, 1KB-run stores  -> FAIL: mchunk mapping only
//     covered m<2048 (bid bit0 unused). Epilogue theory never tested.
// R7: R6 with bijective mapping: mchunk = bits{4,3,0} (8 values), nslab = bid>>5.

#define BATCH 4
#define NN 4096
#define MM 4096
#define DD 64

typedef __attribute__((ext_vector_type(8))) short bf16x8;
typedef __attribute__((ext_vector_type(4))) float f32x4;

__device__ __forceinline__ unsigned short f2bf(float f) {
    unsigned u = __builtin_bit_cast(unsigned, f);
    u += 0x7FFFu + ((u >> 16) & 1u);   // round-to-nearest-even
    return (unsigned short)(u >> 16);
}

__device__ __forceinline__ bf16x8 load8_bf16(const float* __restrict__ p) {
    f32x4 v0 = *reinterpret_cast<const f32x4*>(p);
    f32x4 v1 = *reinterpret_cast<const f32x4*>(p + 4);
    bf16x8 r;
    r[0] = (short)f2bf(v0[0]); r[1] = (short)f2bf(v0[1]);
    r[2] = (short)f2bf(v0[2]); r[3] = (short)f2bf(v0[3]);
    r[4] = (short)f2bf(v1[0]); r[5] = (short)f2bf(v1[1]);
    r[6] = (short)f2bf(v1[2]); r[7] = (short)f2bf(v1[3]);
    return r;
}

__global__ __launch_bounds__(256, 4) void
SparseMatmul3D_36155034698289_kernel(const float* __restrict__ x,
                                     const float* __restrict__ y,
                                     float* __restrict__ out) {
    const int bid    = blockIdx.x;                   // [0,8192)
    const int b      = (bid & 7) >> 1;               // bits 1-2: 2 XCDs per batch
    const int mchunk = ((bid >> 2) & 6) | (bid & 1); // bits {4,3,0}: [0,8)
    const int nslab  = bid >> 5;                     // bits 5-12: [0,256)
    const int n0     = nslab * 16;
    const int m0g    = mchunk * 512;

    const int tid   = threadIdx.x;
    const int lane  = tid & 63;
    const int w     = tid >> 6;          // 4 waves, each a 128-wide m-window
    const int wm    = w * 128;
    const int row16 = lane & 15;
    const int kgrp  = lane >> 4;

    const float* __restrict__ xb = x + (size_t)b * NN * DD;
    const float* __restrict__ yb = y + (size_t)b * MM * DD;

    __shared__ float lds[16 * 512];      // 32 KB C-tile staging

    // B operand = x rows (n side), shared by all waves
    bf16x8 bfrag[2];
    {
        const float* p = xb + (size_t)(n0 + row16) * DD + kgrp * 8;
        bfrag[0] = load8_bf16(p);
        bfrag[1] = load8_bf16(p + 32);
    }

    f32x4 acc[8];
#pragma unroll
    for (int mt = 0; mt < 8; ++mt) acc[mt] = (f32x4){0.f, 0.f, 0.f, 0.f};

    const float* __restrict__ ybase =
        yb + (size_t)(m0g + wm + row16) * DD + kgrp * 8;

#pragma unroll
    for (int mt = 0; mt < 8; ++mt) {
        bf16x8 af0 = load8_bf16(ybase + (size_t)mt * 16 * DD);
        bf16x8 af1 = load8_bf16(ybase + (size_t)mt * 16 * DD + 32);
        acc[mt] = __builtin_amdgcn_mfma_f32_16x16x32_bf16(af0, bfrag[0], acc[mt], 0, 0, 0);
        acc[mt] = __builtin_amdgcn_mfma_f32_16x16x32_bf16(af1, bfrag[1], acc[mt], 0, 0, 0);
    }

    // Stage C-tile: D layout col=lane&15=n-row, row=kgrp*4+reg=m (4 consecutive m).
    // XOR swizzle spreads the 16 same-column lanes across 8 bank-groups.
    {
        const int swz = (row16 & 7) << 2;
#pragma unroll
        for (int mt = 0; mt < 8; ++mt) {
            const int col = (wm + mt * 16 + kgrp * 4) ^ swz;
            *reinterpret_cast<f32x4*>(&lds[row16 * 512 + col]) = acc[mt];
        }
    }
    __syncthreads();

    // Store: per instr, 64 lanes x 16B = 1KB contiguous within ONE row.
    float* __restrict__ ob = out + (size_t)b * NN * MM;
#pragma unroll
    for (int rs = 0; rs < 8; ++rs) {
        const int row = w * 4 + (rs >> 1);
        const int col = (rs & 1) * 256 + lane * 4;
        const int csw = col ^ ((row & 7) << 2);
        f32x4 v = *reinterpret_cast<const f32x4*>(&lds[row * 512 + csw]);
        *reinterpret_cast<f32x4*>(ob + (size_t)(n0 + row) * MM + m0g + col) = v;
    }
}

extern "C" void kernel_launch(void* const* d_in, const int* in_sizes, int n_in,
                              void* d_out, int out_size, void* d_ws, size_t ws_size,
                              hipStream_t stream) {
    const float* x = (const float*)d_in[0];
    const float* y = (const float*)d_in[1];
    float* out = (float*)d_out;

    dim3 grid(8192);
    dim3 block(256);
    SparseMatmul3D_36155034698289_kernel<<<grid, block, 0, stream>>>(x, y, out);
}

// Round 8
// 91.158 us; speedup vs baseline: 1.5706x; 1.5706x over previous
//
#include <hip/hip_runtime.h>

// SparseMatmul3D: out[b,n,m] = sum_k x[b,n,k] * y[b,m,k]
// B=4, N=M=4096, D=64, fp32 in/out. Write-bound (268 MB out, floor ~38us @7TB/s).
// R1: 128x128 tiles, direct 64B-segment stores    -> 89.7 us (~3.0 TB/s)
// R2: 128x128, LDS-staged full-line stores        -> 94.5 us
// R3: 32-row slabs, lockstep m-walk               -> 163 us (vmcnt serialization:
//     per-chunk load-waits drain prior stores; CU idle)
// R5: slab + stagger                              -> 132 us
// R7: 16x512 tiles, LDS epilogue, 1KB runs, fixed -> 143 us (long read phase ->
//     low store duty cycle). Run-length/channel theories dead.
// R8: duty-cycle theory: 64x64 tile PER WAVE, 4 indep waves/block, no LDS/barriers,
//     ~16 staggered waves/CU -> near-continuous store issue. Loads precede stores.

#define BATCH 4
#define NN 4096
#define MM 4096
#define DD 64

typedef __attribute__((ext_vector_type(8))) short bf16x8;
typedef __attribute__((ext_vector_type(4))) float f32x4;

__device__ __forceinline__ unsigned short f2bf(float f) {
    unsigned u = __builtin_bit_cast(unsigned, f);
    u += 0x7FFFu + ((u >> 16) & 1u);   // round-to-nearest-even
    return (unsigned short)(u >> 16);
}

__device__ __forceinline__ bf16x8 load8_bf16(const float* __restrict__ p) {
    f32x4 v0 = *reinterpret_cast<const f32x4*>(p);
    f32x4 v1 = *reinterpret_cast<const f32x4*>(p + 4);
    bf16x8 r;
    r[0] = (short)f2bf(v0[0]); r[1] = (short)f2bf(v0[1]);
    r[2] = (short)f2bf(v0[2]); r[3] = (short)f2bf(v0[3]);
    r[4] = (short)f2bf(v1[0]); r[5] = (short)f2bf(v1[1]);
    r[6] = (short)f2bf(v1[2]); r[7] = (short)f2bf(v1[3]);
    return r;
}

__global__ __launch_bounds__(256, 4) void
SparseMatmul3D_36155034698289_kernel(const float* __restrict__ x,
                                     const float* __restrict__ y,
                                     float* __restrict__ out) {
    const int bid = blockIdx.x;            // [0,4096)
    const int b   = bid >> 10;             // batch (contiguous dispatch window)
    const int ntl = (bid >> 4) & 63;       // n-tile [0,64)
    const int mc  = bid & 15;              // m-chunk (fastest: adjacent bids adjacent m)

    const int w    = threadIdx.x >> 6;     // 4 independent waves
    const int lane = threadIdx.x & 63;
    const int n0   = ntl * 64;
    const int m0   = (mc * 4 + w) * 64;    // this wave's 64x64 tile

    const int row16 = lane & 15;
    const int kgrp  = lane >> 4;

    const float* __restrict__ xb = x + (size_t)b * NN * DD;
    const float* __restrict__ yb = y + (size_t)b * MM * DD;

    // B operand = x rows (n side): 4 n-subtiles
    bf16x8 bfrag[4][2];
#pragma unroll
    for (int j = 0; j < 4; ++j) {
        const float* p = xb + (size_t)(n0 + j * 16 + row16) * DD + kgrp * 8;
        bfrag[j][0] = load8_bf16(p);
        bfrag[j][1] = load8_bf16(p + 32);
    }

    f32x4 acc[4][4];
#pragma unroll
    for (int i = 0; i < 4; ++i)
#pragma unroll
        for (int j = 0; j < 4; ++j)
            acc[i][j] = (f32x4){0.f, 0.f, 0.f, 0.f};

    // A operand = y rows (m side): 4 m-subtiles, loaded in 2 halves (VGPR cap)
#pragma unroll
    for (int h = 0; h < 2; ++h) {
        bf16x8 af[2][2];
#pragma unroll
        for (int i = 0; i < 2; ++i) {
            const float* p = yb + (size_t)(m0 + (h * 2 + i) * 16 + row16) * DD + kgrp * 8;
            af[i][0] = load8_bf16(p);
            af[i][1] = load8_bf16(p + 32);
        }
#pragma unroll
        for (int ks = 0; ks < 2; ++ks)
#pragma unroll
            for (int i = 0; i < 2; ++i)
#pragma unroll
                for (int j = 0; j < 4; ++j)
                    acc[h * 2 + i][j] = __builtin_amdgcn_mfma_f32_16x16x32_bf16(
                        af[i][ks], bfrag[j][ks], acc[h * 2 + i][j], 0, 0, 0);
    }

    // Stores only at kernel end; no loads follow (no vmcnt serialization).
    // D layout: col = lane&15 = n; row = kgrp*4+reg = m (4 consecutive m).
    float* __restrict__ ob = out + (size_t)b * NN * MM;
#pragma unroll
    for (int j = 0; j < 4; ++j) {
        const int n = n0 + j * 16 + row16;
        float* orow = ob + (size_t)n * MM;
#pragma unroll
        for (int i = 0; i < 4; ++i)
            *reinterpret_cast<f32x4*>(orow + m0 + i * 16 + kgrp * 4) = acc[i][j];
    }
}

extern "C" void kernel_launch(void* const* d_in, const int* in_sizes, int n_in,
                              void* d_out, int out_size, void* d_ws, size_t ws_size,
                              hipStream_t stream) {
    const float* x = (const float*)d_in[0];
    const float* y = (const float*)d_in[1];
    float* out = (float*)d_out;

    dim3 grid(4096);
    dim3 block(256);
    SparseMatmul3D_36155034698289_kernel<<<grid, block, 0, stream>>>(x, y, out);
}

// Round 9
// 89.521 us; speedup vs baseline: 1.5993x; 1.0183x over previous
//
#include <hip/hip_runtime.h>

// SparseMatmul3D: out[b,n,m] = sum_k x[b,n,k] * y[b,m,k]
// B=4, N=M=4096, D=64, fp32 in/out. Write-bound (268 MB out, floor ~38us @7TB/s).
// R1: 128x128 tiles, direct stores                -> 89.7 us (~3.0 TB/s)
// R2: 128x128, LDS-staged full-line stores (+NT)  -> 94.5 us
// R3/R5: slabs (+stagger)                         -> 163/132 us (worst)
// R7: 16x512 tiles, LDS 1KB-run stores            -> 143 us
// R8: 64x64 per-wave tiles, no LDS, 16 waves/CU   -> 91.2 us
//   => three distinct structures pin at 268MB/~2.95TB/s: upstream store order
//      is NOT the lever. Remaining family: L2 writeback policy (dirty lines
//      evict in set-hash order, scrambling the HBM stream).
// R9: R8 + nontemporal (nt) stores only — streaming/evict-first policy so
//     writebacks drain in ~store order. One-variable A/B vs R8.

#define BATCH 4
#define NN 4096
#define MM 4096
#define DD 64

typedef __attribute__((ext_vector_type(8))) short bf16x8;
typedef __attribute__((ext_vector_type(4))) float f32x4;

__device__ __forceinline__ unsigned short f2bf(float f) {
    unsigned u = __builtin_bit_cast(unsigned, f);
    u += 0x7FFFu + ((u >> 16) & 1u);   // round-to-nearest-even
    return (unsigned short)(u >> 16);
}

__device__ __forceinline__ bf16x8 load8_bf16(const float* __restrict__ p) {
    f32x4 v0 = *reinterpret_cast<const f32x4*>(p);
    f32x4 v1 = *reinterpret_cast<const f32x4*>(p + 4);
    bf16x8 r;
    r[0] = (short)f2bf(v0[0]); r[1] = (short)f2bf(v0[1]);
    r[2] = (short)f2bf(v0[2]); r[3] = (short)f2bf(v0[3]);
    r[4] = (short)f2bf(v1[0]); r[5] = (short)f2bf(v1[1]);
    r[6] = (short)f2bf(v1[2]); r[7] = (short)f2bf(v1[3]);
    return r;
}

__global__ __launch_bounds__(256, 4) void
SparseMatmul3D_36155034698289_kernel(const float* __restrict__ x,
                                     const float* __restrict__ y,
                                     float* __restrict__ out) {
    const int bid = blockIdx.x;            // [0,4096)
    const int b   = bid >> 10;             // batch (contiguous dispatch window)
    const int ntl = (bid >> 4) & 63;       // n-tile [0,64)
    const int mc  = bid & 15;              // m-chunk (fastest: adjacent bids adjacent m)

    const int w    = threadIdx.x >> 6;     // 4 independent waves
    const int lane = threadIdx.x & 63;
    const int n0   = ntl * 64;
    const int m0   = (mc * 4 + w) * 64;    // this wave's 64x64 tile

    const int row16 = lane & 15;
    const int kgrp  = lane >> 4;

    const float* __restrict__ xb = x + (size_t)b * NN * DD;
    const float* __restrict__ yb = y + (size_t)b * MM * DD;

    // B operand = x rows (n side): 4 n-subtiles
    bf16x8 bfrag[4][2];
#pragma unroll
    for (int j = 0; j < 4; ++j) {
        const float* p = xb + (size_t)(n0 + j * 16 + row16) * DD + kgrp * 8;
        bfrag[j][0] = load8_bf16(p);
        bfrag[j][1] = load8_bf16(p + 32);
    }

    f32x4 acc[4][4];
#pragma unroll
    for (int i = 0; i < 4; ++i)
#pragma unroll
        for (int j = 0; j < 4; ++j)
            acc[i][j] = (f32x4){0.f, 0.f, 0.f, 0.f};

    // A operand = y rows (m side): 4 m-subtiles, loaded in 2 halves (VGPR cap)
#pragma unroll
    for (int h = 0; h < 2; ++h) {
        bf16x8 af[2][2];
#pragma unroll
        for (int i = 0; i < 2; ++i) {
            const float* p = yb + (size_t)(m0 + (h * 2 + i) * 16 + row16) * DD + kgrp * 8;
            af[i][0] = load8_bf16(p);
            af[i][1] = load8_bf16(p + 32);
        }
#pragma unroll
        for (int ks = 0; ks < 2; ++ks)
#pragma unroll
            for (int i = 0; i < 2; ++i)
#pragma unroll
                for (int j = 0; j < 4; ++j)
                    acc[h * 2 + i][j] = __builtin_amdgcn_mfma_f32_16x16x32_bf16(
                        af[i][ks], bfrag[j][ks], acc[h * 2 + i][j], 0, 0, 0);
    }

    // Stores only at kernel end; nontemporal (nt): streaming / evict-first so
    // L2 writebacks drain in ~store order instead of set-hash order.
    // D layout: col = lane&15 = n; row = kgrp*4+reg = m (4 consecutive m).
    float* __restrict__ ob = out + (size_t)b * NN * MM;
#pragma unroll
    for (int j = 0; j < 4; ++j) {
        const int n = n0 + j * 16 + row16;
        float* orow = ob + (size_t)n * MM;
#pragma unroll
        for (int i = 0; i < 4; ++i)
            __builtin_nontemporal_store(
                acc[i][j], reinterpret_cast<f32x4*>(orow + m0 + i * 16 + kgrp * 4));
    }
}

extern "C" void kernel_launch(void* const* d_in, const int* in_sizes, int n_in,
                              void* d_out, int out_size, void* d_ws, size_t ws_size,
                              hipStream_t stream) {
    const float* x = (const float*)d_in[0];
    const float* y = (const float*)d_in[1];
    float* out = (float*)d_out;

    dim3 grid(4096);
    dim3 block(256);
    SparseMatmul3D_36155034698289_kernel<<<grid, block, 0, stream>>>(x, y, out);
}